// Round 3
// baseline (115.841 us; speedup 1.0000x reference)
//
#include <hip/hip_runtime.h>

#define B   32
#define C   512
#define HID 32
#define HW  3136        // 56*56
#define HW4 784         // HW/4
#define POS 410         // round(0.8*512); threshold = sorted[POS-1]

typedef float f32x4 __attribute__((ext_vector_type(4)));

// ---------------------------------------------------------------------------
// K1': fused copy + per-channel mean. One wave per channel, 4 channels/block.
// grid = B*C/4 = 4096 blocks x 256 threads. out = x written unconditionally;
// channel sums reduced per-wave. Traffic: 205 MB R + 205 MB W.
// ---------------------------------------------------------------------------
__global__ __launch_bounds__(256) void copy_mean_kernel(const float* __restrict__ x,
                                                        float* __restrict__ out,
                                                        float* __restrict__ means) {
    const int wave = threadIdx.x >> 6;            // 0..3
    const int lane = threadIdx.x & 63;
    const int bc   = blockIdx.x * 4 + wave;
    const f32x4* xp = reinterpret_cast<const f32x4*>(x + (size_t)bc * HW);
    f32x4* op = reinterpret_cast<f32x4*>(out + (size_t)bc * HW);
    float s = 0.f;
    for (int i = lane; i < HW4; i += 64) {        // 12-13 float4 per lane
        f32x4 v = xp[i];
        op[i] = v;
        s += (v.x + v.y) + (v.z + v.w);
    }
    #pragma unroll
    for (int off = 32; off > 0; off >>= 1)
        s += __shfl_down(s, off, 64);
    if (lane == 0) means[bc] = s * (1.0f / HW);
}

// ---------------------------------------------------------------------------
// K2: SE excitation + rank-select threshold + mask. grid = B, block = C.
// ---------------------------------------------------------------------------
__global__ __launch_bounds__(512) void se_kernel(const float* __restrict__ means,
                                                 const float* __restrict__ W1,
                                                 const float* __restrict__ W2,
                                                 float* __restrict__ masks) {
    const int b = blockIdx.x;
    const int t = threadIdx.x;          // 0..511
    __shared__ float m[C];
    __shared__ float y1[HID];
    __shared__ float y2[C];
    __shared__ float thr;

    m[t] = means[b * C + t];
    __syncthreads();

    // W1 dot: 16 lanes per hidden unit (h = t>>4, l = t&15), shfl_xor reduce.
    {
        const int h = t >> 4;
        const int l = t & 15;
        const float* w = W1 + h * C;
        float acc = 0.f;
        for (int c = l; c < C; c += 16) acc = fmaf(m[c], w[c], acc);
        #pragma unroll
        for (int off = 8; off > 0; off >>= 1) acc += __shfl_xor(acc, off, 16);
        if (l == 0) y1[h] = fmaxf(acc, 0.f);
    }
    __syncthreads();

    {
        const float* w = W2 + t * HID;
        float acc = 0.f;
        #pragma unroll
        for (int h = 0; h < HID; ++h) acc = fmaf(y1[h], w[h], acc);
        y2[t] = 1.f / (1.f + expf(-acc));
    }
    __syncthreads();

    // rank with index tie-break: exactly one thread has rank == POS-1
    const float v = y2[t];
    int rank = 0;
    for (int j = 0; j < C; ++j) {
        float u = y2[j];                 // broadcast LDS read
        rank += (u < v || (u == v && j < t)) ? 1 : 0;
    }
    if (rank == POS - 1) thr = v;
    __syncthreads();

    masks[b * C + t] = (v <= thr) ? 1.f : 0.f;
}

// ---------------------------------------------------------------------------
// K3': zero-fill masked channels. One wave per channel, 4 channels/block.
// ~20% of waves write 12.25 KB of zeros; rest exit. Pure-write ~41 MB.
// ---------------------------------------------------------------------------
__global__ __launch_bounds__(256) void zero_kernel(const float* __restrict__ masks,
                                                   float* __restrict__ out) {
    const int wave = threadIdx.x >> 6;
    const int lane = threadIdx.x & 63;
    const int bc   = blockIdx.x * 4 + wave;
    if (masks[bc] != 0.f) return;
    f32x4* op = reinterpret_cast<f32x4*>(out + (size_t)bc * HW);
    const f32x4 z = {0.f, 0.f, 0.f, 0.f};
    for (int i = lane; i < HW4; i += 64)
        op[i] = z;
}

extern "C" void kernel_launch(void* const* d_in, const int* in_sizes, int n_in,
                              void* d_out, int out_size, void* d_ws, size_t ws_size,
                              hipStream_t stream) {
    const float* x  = (const float*)d_in[0];
    const float* W1 = (const float*)d_in[1];
    const float* W2 = (const float*)d_in[2];
    float* out = (float*)d_out;

    float* means = (float*)d_ws;                 // B*C floats = 64 KB
    float* masks = means + B * C;                // B*C floats = 64 KB

    copy_mean_kernel<<<B * C / 4, 256, 0, stream>>>(x, out, means);
    se_kernel<<<B, C, 0, stream>>>(means, W1, W2, masks);
    zero_kernel<<<B * C / 4, 256, 0, stream>>>(masks, out);
}

// Round 4
// 99.906 us; speedup vs baseline: 1.1595x; 1.1595x over previous
//
#include <hip/hip_runtime.h>

#define B   32
#define C   512
#define HID 32
#define HW  3136        // 56*56
#define HW4 784         // HW/4
#define POS 410         // round(0.8*512); threshold = sorted[POS-1]

typedef float f32x4 __attribute__((ext_vector_type(4)));

// ---------------------------------------------------------------------------
// K1'': fused copy + per-channel mean, one 256-thread block per channel.
// grid = B*C = 16384 blocks (matches R2-K3's proven 5.9+ TB/s shape).
// Fully unrolled 3(+1 tail) f32x4 iters: all loads issued before stores
// (max memory-level parallelism); non-temporal on both streams (never
// re-read -> no L2/L3 pollution). Then wave shfl + LDS reduce for the sum.
// ---------------------------------------------------------------------------
__global__ __launch_bounds__(256) void copy_mean_kernel(const float* __restrict__ x,
                                                        float* __restrict__ out,
                                                        float* __restrict__ means) {
    const int bc  = blockIdx.x;
    const int tid = threadIdx.x;
    const f32x4* xp = reinterpret_cast<const f32x4*>(x + (size_t)bc * HW);
    f32x4* op = reinterpret_cast<f32x4*>(out + (size_t)bc * HW);

    const bool tail = tid < (HW4 - 3 * 256);      // 16 threads take a 4th vec
    f32x4 v0 = __builtin_nontemporal_load(xp + tid);
    f32x4 v1 = __builtin_nontemporal_load(xp + tid + 256);
    f32x4 v2 = __builtin_nontemporal_load(xp + tid + 512);
    f32x4 v3 = {0.f, 0.f, 0.f, 0.f};
    if (tail) v3 = __builtin_nontemporal_load(xp + tid + 768);

    __builtin_nontemporal_store(v0, op + tid);
    __builtin_nontemporal_store(v1, op + tid + 256);
    __builtin_nontemporal_store(v2, op + tid + 512);
    if (tail) __builtin_nontemporal_store(v3, op + tid + 768);

    float s = (v0.x + v0.y) + (v0.z + v0.w)
            + (v1.x + v1.y) + (v1.z + v1.w)
            + (v2.x + v2.y) + (v2.z + v2.w)
            + (v3.x + v3.y) + (v3.z + v3.w);

    #pragma unroll
    for (int off = 32; off > 0; off >>= 1)
        s += __shfl_down(s, off, 64);
    __shared__ float red[4];
    if ((tid & 63) == 0) red[tid >> 6] = s;
    __syncthreads();
    if (tid == 0)
        means[bc] = ((red[0] + red[1]) + (red[2] + red[3])) * (1.0f / HW);
}

// ---------------------------------------------------------------------------
// K2: SE excitation + rank-select threshold + mask. grid = B, block = C.
// ---------------------------------------------------------------------------
__global__ __launch_bounds__(512) void se_kernel(const float* __restrict__ means,
                                                 const float* __restrict__ W1,
                                                 const float* __restrict__ W2,
                                                 float* __restrict__ masks) {
    const int b = blockIdx.x;
    const int t = threadIdx.x;          // 0..511
    __shared__ float m[C];
    __shared__ float y1[HID];
    __shared__ float y2[C];
    __shared__ float thr;

    m[t] = means[b * C + t];
    __syncthreads();

    // W1 dot: 16 lanes per hidden unit (h = t>>4, l = t&15), shfl_xor reduce.
    {
        const int h = t >> 4;
        const int l = t & 15;
        const float* w = W1 + h * C;
        float acc = 0.f;
        for (int c = l; c < C; c += 16) acc = fmaf(m[c], w[c], acc);
        #pragma unroll
        for (int off = 8; off > 0; off >>= 1) acc += __shfl_xor(acc, off, 16);
        if (l == 0) y1[h] = fmaxf(acc, 0.f);
    }
    __syncthreads();

    {
        const float* w = W2 + t * HID;
        float acc = 0.f;
        #pragma unroll
        for (int h = 0; h < HID; ++h) acc = fmaf(y1[h], w[h], acc);
        y2[t] = 1.f / (1.f + expf(-acc));
    }
    __syncthreads();

    // rank with index tie-break: exactly one thread has rank == POS-1
    const float v = y2[t];
    int rank = 0;
    for (int j = 0; j < C; ++j) {
        float u = y2[j];                 // broadcast LDS read
        rank += (u < v || (u == v && j < t)) ? 1 : 0;
    }
    if (rank == POS - 1) thr = v;
    __syncthreads();

    masks[b * C + t] = (v <= thr) ? 1.f : 0.f;
}

// ---------------------------------------------------------------------------
// K3': zero-fill masked channels. One wave per channel, 4 channels/block.
// ~20% of waves write 12.25 KB of zeros; rest exit. Pure-write ~41 MB.
// ---------------------------------------------------------------------------
__global__ __launch_bounds__(256) void zero_kernel(const float* __restrict__ masks,
                                                   float* __restrict__ out) {
    const int wave = threadIdx.x >> 6;
    const int lane = threadIdx.x & 63;
    const int bc   = blockIdx.x * 4 + wave;
    if (masks[bc] != 0.f) return;
    f32x4* op = reinterpret_cast<f32x4*>(out + (size_t)bc * HW);
    const f32x4 z = {0.f, 0.f, 0.f, 0.f};
    for (int i = lane; i < HW4; i += 64)
        __builtin_nontemporal_store(z, op + i);
}

extern "C" void kernel_launch(void* const* d_in, const int* in_sizes, int n_in,
                              void* d_out, int out_size, void* d_ws, size_t ws_size,
                              hipStream_t stream) {
    const float* x  = (const float*)d_in[0];
    const float* W1 = (const float*)d_in[1];
    const float* W2 = (const float*)d_in[2];
    float* out = (float*)d_out;

    float* means = (float*)d_ws;                 // B*C floats = 64 KB
    float* masks = means + B * C;                // B*C floats = 64 KB

    copy_mean_kernel<<<B * C, 256, 0, stream>>>(x, out, means);
    se_kernel<<<B, C, 0, stream>>>(means, W1, W2, masks);
    zero_kernel<<<B * C / 4, 256, 0, stream>>>(masks, out);
}

// Round 5
// 96.683 us; speedup vs baseline: 1.1981x; 1.0333x over previous
//
#include <hip/hip_runtime.h>

#define B   32
#define C   512
#define HID 32
#define HW  3136        // 56*56
#define HW4 784         // HW/4
#define POS 410         // round(0.8*512); threshold = sorted[POS-1]

typedef float f32x4 __attribute__((ext_vector_type(4)));

// ---------------------------------------------------------------------------
// K1: fused copy + per-channel mean, one 256-thread block per channel.
// grid = B*C = 16384 blocks. PLAIN loads (L2 line aggregation; nt loads
// bypass L2 and measured ~5.1 TB/s vs 6.3 ceiling), NT stores (no
// write-allocate pollution). All loads issued before all stores (MLP).
// ---------------------------------------------------------------------------
__global__ __launch_bounds__(256) void copy_mean_kernel(const float* __restrict__ x,
                                                        float* __restrict__ out,
                                                        float* __restrict__ means) {
    const int bc  = blockIdx.x;
    const int tid = threadIdx.x;
    const f32x4* xp = reinterpret_cast<const f32x4*>(x + (size_t)bc * HW);
    f32x4* op = reinterpret_cast<f32x4*>(out + (size_t)bc * HW);

    const bool tail = tid < (HW4 - 3 * 256);      // 16 threads take a 4th vec
    f32x4 v0 = xp[tid];
    f32x4 v1 = xp[tid + 256];
    f32x4 v2 = xp[tid + 512];
    f32x4 v3 = {0.f, 0.f, 0.f, 0.f};
    if (tail) v3 = xp[tid + 768];

    __builtin_nontemporal_store(v0, op + tid);
    __builtin_nontemporal_store(v1, op + tid + 256);
    __builtin_nontemporal_store(v2, op + tid + 512);
    if (tail) __builtin_nontemporal_store(v3, op + tid + 768);

    float s = (v0.x + v0.y) + (v0.z + v0.w)
            + (v1.x + v1.y) + (v1.z + v1.w)
            + (v2.x + v2.y) + (v2.z + v2.w)
            + (v3.x + v3.y) + (v3.z + v3.w);

    #pragma unroll
    for (int off = 32; off > 0; off >>= 1)
        s += __shfl_down(s, off, 64);
    __shared__ float red[4];
    if ((tid & 63) == 0) red[tid >> 6] = s;
    __syncthreads();
    if (tid == 0)
        means[bc] = ((red[0] + red[1]) + (red[2] + red[3])) * (1.0f / HW);
}

// ---------------------------------------------------------------------------
// K2: SE excitation + rank-select threshold + mask. grid = B, block = C.
// ---------------------------------------------------------------------------
__global__ __launch_bounds__(512) void se_kernel(const float* __restrict__ means,
                                                 const float* __restrict__ W1,
                                                 const float* __restrict__ W2,
                                                 float* __restrict__ masks) {
    const int b = blockIdx.x;
    const int t = threadIdx.x;          // 0..511
    __shared__ float m[C];
    __shared__ float y1[HID];
    __shared__ float y2[C];
    __shared__ float thr;

    m[t] = means[b * C + t];
    __syncthreads();

    // W1 dot: 16 lanes per hidden unit (h = t>>4, l = t&15), shfl_xor reduce.
    {
        const int h = t >> 4;
        const int l = t & 15;
        const float* w = W1 + h * C;
        float acc = 0.f;
        for (int c = l; c < C; c += 16) acc = fmaf(m[c], w[c], acc);
        #pragma unroll
        for (int off = 8; off > 0; off >>= 1) acc += __shfl_xor(acc, off, 16);
        if (l == 0) y1[h] = fmaxf(acc, 0.f);
    }
    __syncthreads();

    {
        const float* w = W2 + t * HID;
        float acc = 0.f;
        #pragma unroll
        for (int h = 0; h < HID; ++h) acc = fmaf(y1[h], w[h], acc);
        y2[t] = 1.f / (1.f + expf(-acc));
    }
    __syncthreads();

    // rank with index tie-break: exactly one thread has rank == POS-1
    const float v = y2[t];
    int rank = 0;
    for (int j = 0; j < C; ++j) {
        float u = y2[j];                 // broadcast LDS read
        rank += (u < v || (u == v && j < t)) ? 1 : 0;
    }
    if (rank == POS - 1) thr = v;
    __syncthreads();

    masks[b * C + t] = (v <= thr) ? 1.f : 0.f;
}

// ---------------------------------------------------------------------------
// K3: zero-fill masked channels. One wave per channel, 4 channels/block.
// ~20% of waves write 12.25 KB of zeros; rest exit. Pure-write ~41 MB.
// ---------------------------------------------------------------------------
__global__ __launch_bounds__(256) void zero_kernel(const float* __restrict__ masks,
                                                   float* __restrict__ out) {
    const int wave = threadIdx.x >> 6;
    const int lane = threadIdx.x & 63;
    const int bc   = blockIdx.x * 4 + wave;
    if (masks[bc] != 0.f) return;
    f32x4* op = reinterpret_cast<f32x4*>(out + (size_t)bc * HW);
    const f32x4 z = {0.f, 0.f, 0.f, 0.f};
    for (int i = lane; i < HW4; i += 64)
        __builtin_nontemporal_store(z, op + i);
}

extern "C" void kernel_launch(void* const* d_in, const int* in_sizes, int n_in,
                              void* d_out, int out_size, void* d_ws, size_t ws_size,
                              hipStream_t stream) {
    const float* x  = (const float*)d_in[0];
    const float* W1 = (const float*)d_in[1];
    const float* W2 = (const float*)d_in[2];
    float* out = (float*)d_out;

    float* means = (float*)d_ws;                 // B*C floats = 64 KB
    float* masks = means + B * C;                // B*C floats = 64 KB

    copy_mean_kernel<<<B * C, 256, 0, stream>>>(x, out, means);
    se_kernel<<<B, C, 0, stream>>>(means, W1, W2, masks);
    zero_kernel<<<B * C / 4, 256, 0, stream>>>(masks, out);
}